// Round 13
// baseline (265.529 us; speedup 1.0000x reference)
//
#include <hip/hip_runtime.h>

#define N_NODES 100000
#define N_EDGES 1250000
#define D 64
#define ED 32
#define CAP 32          // bucket = 32 slots * 8B = 256B line-aligned; overflow handled
#define OVF_CAP 131072

typedef unsigned int uint;
typedef unsigned short ushort;

__device__ __forceinline__ uint bfr(float f) {
    uint u = __float_as_uint(f);
    return (u + 0x7FFFu + ((u >> 16) & 1u)) >> 16;
}
__device__ __forceinline__ float bflo(uint v) { return __uint_as_float(v << 16); }
__device__ __forceinline__ float bfhi(uint v) { return __uint_as_float(v & 0xffff0000u); }
__device__ __forceinline__ float bfu(ushort s) { return __uint_as_float(((uint)s) << 16); }

// ---------------- bucket scatter: 1 edge/thread, all atomics concurrent ----------------

__global__ void __launch_bounds__(256) scatter_bucket_k(const int* __restrict__ row,
                                                        const int* __restrict__ col,
                                                        int* __restrict__ cursor,   // zeroed; becomes deg
                                                        int2* __restrict__ erec,
                                                        int4* __restrict__ ovf,
                                                        int* __restrict__ ovfcnt) {
    int i = blockIdx.x * blockDim.x + threadIdx.x;
    const int stride = gridDim.x * blockDim.x;
    for (int e = i; e < N_EDGES; e += stride) {
        const int c = col[e];
        const int r = row[e];
        const int pos = atomicAdd(&cursor[c], 1);
        if (pos < CAP) {
            erec[((size_t)c << 5) + pos] = make_int2(r, e);
        } else {
            const int o = atomicAdd(ovfcnt, 1);
            if (o < OVF_CAP) ovf[o] = make_int4(c, r, e, 0);
        }
    }
}

// ---------------- xl16 = bf16(x @ lw^T) (blocks 0..1023) | Cmat,lwb (block 1024) ----------------

__global__ void __launch_bounds__(256) xl16_combine_k(const float* __restrict__ x,
                                                      const float* __restrict__ lw,
                                                      ushort* __restrict__ xl,
                                                      const float* __restrict__ ew,
                                                      const float* __restrict__ eb,
                                                      float* __restrict__ Cmat,
                                                      float* __restrict__ lwb) {
    const int bid = blockIdx.x;
    if (bid < 1024) {
        const int lane = threadIdx.x & 63;
        const int wid  = bid * 4 + (threadIdx.x >> 6);
        const int nw   = 1024 * 4;

        float w[D];
        const float4* lw4 = (const float4*)(lw + (size_t)lane * D);
#pragma unroll
        for (int q = 0; q < D / 4; ++q) {
            const float4 v = lw4[q];
            w[4*q+0] = v.x; w[4*q+1] = v.y; w[4*q+2] = v.z; w[4*q+3] = v.w;
        }
        for (int n = wid; n < N_NODES; n += nw) {
            const float4* xx = (const float4*)(x + (size_t)n * D);
            float d0 = 0.f, d1 = 0.f;
#pragma unroll
            for (int q = 0; q < D / 8; ++q) {
                const float4 v0 = xx[q];
                const float4 v1 = xx[q + 8];
                d0 = fmaf(v0.x, w[4*q+0], d0);  d0 = fmaf(v0.y, w[4*q+1], d0);
                d0 = fmaf(v0.z, w[4*q+2], d0);  d0 = fmaf(v0.w, w[4*q+3], d0);
                d1 = fmaf(v1.x, w[4*q+32], d1); d1 = fmaf(v1.y, w[4*q+33], d1);
                d1 = fmaf(v1.z, w[4*q+34], d1); d1 = fmaf(v1.w, w[4*q+35], d1);
            }
            xl[(size_t)n * D + lane] = (ushort)bfr(d0 + d1);
        }
    } else {
        for (int idx = threadIdx.x; idx < D * ED; idx += 256) {
            const int d = idx >> 5, j = idx & 31;
            float s = 0.f;
#pragma unroll
            for (int k = 0; k < D; ++k) s = fmaf(lw[d * D + k], ew[k * ED + j], s);
            Cmat[idx] = s;
        }
        if (threadIdx.x < D) {
            float s = 0.f;
#pragma unroll
            for (int k = 0; k < D; ++k) s = fmaf(lw[threadIdx.x * D + k], eb[k], s);
            lwb[threadIdx.x] = s;
        }
    }
}

// ---------------- aggregation + epilogue v6 (permuted dim ownership) ----------------
// Lane l owns output dim perm(l) = 2*(l&31) + (l>>5) — exactly where the packed
// xl accumulators land after the half-combine, so no repack shuffles.

__global__ void __launch_bounds__(256) agg_v6_k(const ushort* __restrict__ xl,
                                                const float* __restrict__ ea,
                                                const int* __restrict__ deg_,
                                                const int2* __restrict__ erec,
                                                const int4* __restrict__ ovf,
                                                const int* __restrict__ ovfcnt,
                                                const float* __restrict__ Cmat,
                                                const float* __restrict__ lwb,
                                                const float* __restrict__ lb,
                                                float* __restrict__ out) {
    const int lane = threadIdx.x & 63;
    const int half = lane >> 5;
    const int s31  = lane & 31;
    const int dimp = 2 * s31 + half;       // owned output dim
    const int wid  = blockIdx.x * (blockDim.x >> 6) + (threadIdx.x >> 6);
    const int nw   = gridDim.x * (blockDim.x >> 6);

    const float lwbl = lwb[dimp];
    const float lbl  = lb[dimp];
    float w[ED];                           // Cmat row for owned dim (L1-hot source)
    const float4* cm4 = (const float4*)(Cmat + (size_t)dimp * ED);
#pragma unroll
    for (int q = 0; q < ED / 4; ++q) {
        const float4 v = cm4[q];
        w[4*q+0] = v.x; w[4*q+1] = v.y; w[4*q+2] = v.z; w[4*q+3] = v.w;
    }
    const int novf = min(*ovfcnt, OVF_CAP);

    for (int n = wid; n < N_NODES; n += nw) {
        const int deg  = deg_[n];
        const int degb = min(deg, CAP);

        float axl = 0.f, axh = 0.f;        // packed: dims {2*s31, 2*s31+1}, this half's rows
        float ae[4] = {0.f, 0.f, 0.f, 0.f};

        if (degb > 0) {
            const int2 rec = erec[((size_t)n << 5) + min(s31, degb - 1)];  // 256B bucket

            for (int base = 0; base < degb; base += 16) {   // <= 2 wave-uniform iters
                uint  vx[8];
                float ve[8];
#pragma unroll
                for (int i = 0; i < 8; ++i) {               // xl: rows base+2i+half
                    const int r = base + 2 * i + half;
                    const int nsrc = __shfl(rec.x, min(r, degb - 1));
                    vx[i] = *(const uint*)(xl + (size_t)nsrc * D + s31 * 2);
                }
#pragma unroll
                for (int i = 0; i < 8; ++i) {               // ea: rows base+2i+half
                    const int r = base + 2 * i + half;
                    const int esrc = __shfl(rec.y, min(r, degb - 1));
                    ve[i] = ea[(size_t)esrc * ED + s31];
                }
#pragma unroll
                for (int i = 0; i < 8; ++i) {
                    const bool p = (base + 2 * i + half) < degb;
                    axl += p ? bflo(vx[i]) : 0.f;
                    axh += p ? bfhi(vx[i]) : 0.f;
                }
#pragma unroll
                for (int i = 0; i < 8; ++i) {
                    const bool p = (base + 2 * i + half) < degb;
                    ae[i & 3] += p ? ve[i] : 0.f;
                }
            }
        }

        // ---- overflow edges (correctness path; empty in practice); half 0 adds once ----
        if (novf > 0) {
            for (int o = 0; o < novf; ++o) {
                const int4 v = ovf[o];
                if (v.x == n && half == 0) {
                    const uint u = *(const uint*)(xl + (size_t)v.y * D + s31 * 2);
                    axl += bflo(u); axh += bfhi(u);
                    ae[0] += ea[(size_t)v.z * ED + s31];
                }
            }
        }

        // ---- combine halves; axl/axh now live exactly at the owned dims ----
        axl += __shfl_xor(axl, 32);           // segsum(xl)[n][2*s31]
        axh += __shfl_xor(axh, 32);           // segsum(xl)[n][2*s31+1]
        float aes = (ae[0] + ae[1]) + (ae[2] + ae[3]);
        aes += __shfl_xor(aes, 32);           // segsum(ea)[n][s31], replicated

        float zd = half ? axh : axl;          // no repack shuffles
#pragma unroll
        for (int q = 0; q < ED / 4; ++q) {
            zd = fmaf(__shfl(aes, 4*q+0), w[4*q+0], zd);
            zd = fmaf(__shfl(aes, 4*q+1), w[4*q+1], zd);
            zd = fmaf(__shfl(aes, 4*q+2), w[4*q+2], zd);
            zd = fmaf(__shfl(aes, 4*q+3), w[4*q+3], zd);
        }
        const float inv = 1.f / fmaxf((float)deg, 1.f);
        out[(size_t)n * D + dimp] = fmaf(inv, zd, (deg > 0 ? lwbl : 0.f) + lbl);
    }
}

// ---------------- tier C (tiny ws): atomic version ----------------

__global__ void __launch_bounds__(256) edge_scatter_fb(
    const float* __restrict__ x, const int* __restrict__ ei,
    const float* __restrict__ ea, const float* __restrict__ ew,
    const float* __restrict__ eb, float* __restrict__ agg, float* __restrict__ deg) {
    const int lane = threadIdx.x & 63;
    const int wid  = blockIdx.x * (blockDim.x >> 6) + (threadIdx.x >> 6);
    const int nw   = gridDim.x * (blockDim.x >> 6);
    float w[ED];
#pragma unroll
    for (int k = 0; k < ED; ++k) w[k] = ew[lane * ED + k];
    const float b = eb[lane];
    for (int e = wid; e < N_EDGES; e += nw) {
        const int r = ei[e];
        const int c = ei[N_EDGES + e];
        const float4* ea4 = (const float4*)(ea + (size_t)e * ED);
        float acc = b;
#pragma unroll
        for (int q = 0; q < ED / 4; ++q) {
            float4 v = ea4[q];
            acc = fmaf(v.x, w[4*q+0], acc); acc = fmaf(v.y, w[4*q+1], acc);
            acc = fmaf(v.z, w[4*q+2], acc); acc = fmaf(v.w, w[4*q+3], acc);
        }
        acc += x[(size_t)r * D + lane];
        atomicAdd(&agg[(size_t)c * D + lane], acc);
        if (lane == 0) atomicAdd(&deg[c], 1.0f);
    }
}

__global__ void __launch_bounds__(256) node_linear_fb(
    float* __restrict__ agg, const float* __restrict__ deg,
    const float* __restrict__ lw, const float* __restrict__ lb) {
    const int lane = threadIdx.x & 63;
    const int wid  = blockIdx.x * (blockDim.x >> 6) + (threadIdx.x >> 6);
    const int nw   = gridDim.x * (blockDim.x >> 6);
    float w[D];
#pragma unroll
    for (int k = 0; k < D; ++k) w[k] = lw[lane * D + k];
    const float b = lb[lane];
    for (int n = wid; n < N_NODES; n += nw) {
        const float inv = 1.0f / fmaxf(deg[n], 1.0f);
        const float4* a4 = (const float4*)(agg + (size_t)n * D);
        float dot = 0.0f;
#pragma unroll
        for (int q = 0; q < D / 4; ++q) {
            float4 v = a4[q];
            dot = fmaf(v.x, w[4*q+0], dot); dot = fmaf(v.y, w[4*q+1], dot);
            dot = fmaf(v.z, w[4*q+2], dot); dot = fmaf(v.w, w[4*q+3], dot);
        }
        agg[(size_t)n * D + lane] = fmaf(inv, dot, b);
    }
}

// ---------------- launch ----------------

extern "C" void kernel_launch(void* const* d_in, const int* in_sizes, int n_in,
                              void* d_out, int out_size, void* d_ws, size_t ws_size,
                              hipStream_t stream) {
    const float* x  = (const float*)d_in[0];
    const int*   ei = (const int*)d_in[1];     // [2][E]: rows then cols
    const float* ea = (const float*)d_in[2];
    const float* lw = (const float*)d_in[3];
    const float* lb = (const float*)d_in[4];
    const float* ew = (const float*)d_in[5];
    const float* eb = (const float*)d_in[6];
    const int* row = ei;
    const int* col = ei + N_EDGES;

    char* ws = (char*)d_ws;
    float* zout = (float*)d_out;

    // ws layout (~41 MB)
    const size_t W_EREC = 0;                                   // N*32 int2 = 25,600,000
    const size_t W_XL   = (size_t)N_NODES * CAP * 8;           // N*64 bf16 = 12,800,000
    const size_t W_CNT  = W_XL + (size_t)N_NODES * D * 2;      //    400,000
    const size_t W_OVFC = W_CNT + (size_t)N_NODES * 4;         //         16
    const size_t W_OVF  = W_OVFC + 16;                         //  2,097,152
    const size_t W_CMAT = W_OVF + (size_t)OVF_CAP * 16;        //      8,192
    const size_t W_LWB  = W_CMAT + D * ED * 4;                 //        256
    const size_t REQ    = W_LWB + D * 4;

    if (ws_size >= REQ) {
        int2*   erec = (int2*)(ws + W_EREC);
        ushort* xl   = (ushort*)(ws + W_XL);
        int*    cnt  = (int*)(ws + W_CNT);
        int*    ovfc = (int*)(ws + W_OVFC);
        int4*   ovf  = (int4*)(ws + W_OVF);
        float*  Cmat = (float*)(ws + W_CMAT);
        float*  lwbv = (float*)(ws + W_LWB);

        hipMemsetAsync(cnt, 0, (size_t)N_NODES * sizeof(int) + 16, stream);
        scatter_bucket_k<<<8192, 256, 0, stream>>>(row, col, cnt, erec, ovf, ovfc);
        xl16_combine_k  <<<1025, 256, 0, stream>>>(x, lw, xl, ew, eb, Cmat, lwbv);
        agg_v6_k        <<<4096, 256, 0, stream>>>(xl, ea, cnt, erec, ovf, ovfc,
                                                   Cmat, lwbv, lb, zout);
    } else {
        float* deg = (float*)d_ws;
        hipMemsetAsync(zout, 0, (size_t)N_NODES * D * sizeof(float), stream);
        hipMemsetAsync(deg, 0, (size_t)N_NODES * sizeof(float), stream);
        edge_scatter_fb<<<2048, 256, 0, stream>>>(x, ei, ea, ew, eb, zout, deg);
        node_linear_fb <<<1024, 256, 0, stream>>>(zout, deg, lw, lb);
    }
}

// Round 14
// 223.287 us; speedup vs baseline: 1.1892x; 1.1892x over previous
//
#include <hip/hip_runtime.h>

#define N_NODES 100000
#define N_EDGES 1250000
#define D 64
#define ED 32
#define CAP 32          // bucket = 32 slots * 8B = 256B line-aligned; overflow handled
#define OVF_CAP 131072
#define NXCD 8
#define NPG (N_NODES / NXCD)   // 12500 destinations per XCD group

typedef unsigned int uint;
typedef unsigned short ushort;

__device__ __forceinline__ uint bfr(float f) {
    uint u = __float_as_uint(f);
    return (u + 0x7FFFu + ((u >> 16) & 1u)) >> 16;
}
__device__ __forceinline__ float bflo(uint v) { return __uint_as_float(v << 16); }
__device__ __forceinline__ float bfhi(uint v) { return __uint_as_float(v & 0xffff0000u); }
__device__ __forceinline__ float bfu(ushort s) { return __uint_as_float(((uint)s) << 16); }

// ---------------- XCD-partitioned bucket scatter ----------------
// Blocks with bid%8==g handle destinations [g*12500,(g+1)*12500): the erec slice
// (3.2MB) and cursor slice (50KB) stay in that XCD's L2, so the ~12.5 writes per
// bucket line merge before writeback (kills the cross-XCD write amplification).

__global__ void __launch_bounds__(256) scatter_xcd_k(const int* __restrict__ row,
                                                     const int* __restrict__ col,
                                                     int* __restrict__ cursor,   // zeroed; becomes deg
                                                     int2* __restrict__ erec,
                                                     int4* __restrict__ ovf,
                                                     int* __restrict__ ovfcnt) {
    const int g   = blockIdx.x & (NXCD - 1);          // XCD proxy (round-robin dispatch)
    const int sub = blockIdx.x >> 3;                  // block index within group
    const int tid = sub * blockDim.x + threadIdx.x;
    const int stride = (gridDim.x >> 3) * blockDim.x;
    const int lo = g * NPG, hi = lo + NPG;

    for (int e = tid; e < N_EDGES; e += stride) {
        const int c = col[e];                         // coalesced; L3-served across groups
        if (c >= lo && c < hi) {
            const int r = row[e];
            const int pos = atomicAdd(&cursor[c], 1); // L2-local to this XCD
            if (pos < CAP) {
                erec[((size_t)c << 5) + pos] = make_int2(r, e);
            } else {
                const int o = atomicAdd(ovfcnt, 1);
                if (o < OVF_CAP) ovf[o] = make_int4(c, r, e, 0);
            }
        }
    }
}

// ---------------- xl16 = bf16(x @ lw^T) (blocks 0..1023) | Cmat,lwb (block 1024) ----------------

__global__ void __launch_bounds__(256) xl16_combine_k(const float* __restrict__ x,
                                                      const float* __restrict__ lw,
                                                      ushort* __restrict__ xl,
                                                      const float* __restrict__ ew,
                                                      const float* __restrict__ eb,
                                                      float* __restrict__ Cmat,
                                                      float* __restrict__ lwb) {
    const int bid = blockIdx.x;
    if (bid < 1024) {
        const int lane = threadIdx.x & 63;
        const int wid  = bid * 4 + (threadIdx.x >> 6);
        const int nw   = 1024 * 4;

        float w[D];
        const float4* lw4 = (const float4*)(lw + (size_t)lane * D);
#pragma unroll
        for (int q = 0; q < D / 4; ++q) {
            const float4 v = lw4[q];
            w[4*q+0] = v.x; w[4*q+1] = v.y; w[4*q+2] = v.z; w[4*q+3] = v.w;
        }
        for (int n = wid; n < N_NODES; n += nw) {
            const float4* xx = (const float4*)(x + (size_t)n * D);
            float d0 = 0.f, d1 = 0.f;
#pragma unroll
            for (int q = 0; q < D / 8; ++q) {
                const float4 v0 = xx[q];
                const float4 v1 = xx[q + 8];
                d0 = fmaf(v0.x, w[4*q+0], d0);  d0 = fmaf(v0.y, w[4*q+1], d0);
                d0 = fmaf(v0.z, w[4*q+2], d0);  d0 = fmaf(v0.w, w[4*q+3], d0);
                d1 = fmaf(v1.x, w[4*q+32], d1); d1 = fmaf(v1.y, w[4*q+33], d1);
                d1 = fmaf(v1.z, w[4*q+34], d1); d1 = fmaf(v1.w, w[4*q+35], d1);
            }
            xl[(size_t)n * D + lane] = (ushort)bfr(d0 + d1);
        }
    } else {
        for (int idx = threadIdx.x; idx < D * ED; idx += 256) {
            const int d = idx >> 5, j = idx & 31;
            float s = 0.f;
#pragma unroll
            for (int k = 0; k < D; ++k) s = fmaf(lw[d * D + k], ew[k * ED + j], s);
            Cmat[idx] = s;
        }
        if (threadIdx.x < D) {
            float s = 0.f;
#pragma unroll
            for (int k = 0; k < D; ++k) s = fmaf(lw[threadIdx.x * D + k], eb[k], s);
            lwb[threadIdx.x] = s;
        }
    }
}

// ---------------- aggregation + epilogue v6 (permuted dim ownership) ----------------

__global__ void __launch_bounds__(256) agg_v6_k(const ushort* __restrict__ xl,
                                                const float* __restrict__ ea,
                                                const int* __restrict__ deg_,
                                                const int2* __restrict__ erec,
                                                const int4* __restrict__ ovf,
                                                const int* __restrict__ ovfcnt,
                                                const float* __restrict__ Cmat,
                                                const float* __restrict__ lwb,
                                                const float* __restrict__ lb,
                                                float* __restrict__ out) {
    const int lane = threadIdx.x & 63;
    const int half = lane >> 5;
    const int s31  = lane & 31;
    const int dimp = 2 * s31 + half;       // owned output dim
    const int wid  = blockIdx.x * (blockDim.x >> 6) + (threadIdx.x >> 6);
    const int nw   = gridDim.x * (blockDim.x >> 6);

    const float lwbl = lwb[dimp];
    const float lbl  = lb[dimp];
    float w[ED];
    const float4* cm4 = (const float4*)(Cmat + (size_t)dimp * ED);
#pragma unroll
    for (int q = 0; q < ED / 4; ++q) {
        const float4 v = cm4[q];
        w[4*q+0] = v.x; w[4*q+1] = v.y; w[4*q+2] = v.z; w[4*q+3] = v.w;
    }
    const int novf = min(*ovfcnt, OVF_CAP);

    for (int n = wid; n < N_NODES; n += nw) {
        const int deg  = deg_[n];
        const int degb = min(deg, CAP);

        float axl = 0.f, axh = 0.f;
        float ae[4] = {0.f, 0.f, 0.f, 0.f};

        if (degb > 0) {
            const int2 rec = erec[((size_t)n << 5) + min(s31, degb - 1)];

            for (int base = 0; base < degb; base += 16) {   // <= 2 wave-uniform iters
                uint  vx[8];
                float ve[8];
#pragma unroll
                for (int i = 0; i < 8; ++i) {
                    const int r = base + 2 * i + half;
                    const int nsrc = __shfl(rec.x, min(r, degb - 1));
                    vx[i] = *(const uint*)(xl + (size_t)nsrc * D + s31 * 2);
                }
#pragma unroll
                for (int i = 0; i < 8; ++i) {
                    const int r = base + 2 * i + half;
                    const int esrc = __shfl(rec.y, min(r, degb - 1));
                    ve[i] = ea[(size_t)esrc * ED + s31];
                }
#pragma unroll
                for (int i = 0; i < 8; ++i) {
                    const bool p = (base + 2 * i + half) < degb;
                    axl += p ? bflo(vx[i]) : 0.f;
                    axh += p ? bfhi(vx[i]) : 0.f;
                }
#pragma unroll
                for (int i = 0; i < 8; ++i) {
                    const bool p = (base + 2 * i + half) < degb;
                    ae[i & 3] += p ? ve[i] : 0.f;
                }
            }
        }

        if (novf > 0) {
            for (int o = 0; o < novf; ++o) {
                const int4 v = ovf[o];
                if (v.x == n && half == 0) {
                    const uint u = *(const uint*)(xl + (size_t)v.y * D + s31 * 2);
                    axl += bflo(u); axh += bfhi(u);
                    ae[0] += ea[(size_t)v.z * ED + s31];
                }
            }
        }

        axl += __shfl_xor(axl, 32);           // segsum(xl)[n][2*s31]
        axh += __shfl_xor(axh, 32);           // segsum(xl)[n][2*s31+1]
        float aes = (ae[0] + ae[1]) + (ae[2] + ae[3]);
        aes += __shfl_xor(aes, 32);           // segsum(ea)[n][s31]

        float zd = half ? axh : axl;
#pragma unroll
        for (int q = 0; q < ED / 4; ++q) {
            zd = fmaf(__shfl(aes, 4*q+0), w[4*q+0], zd);
            zd = fmaf(__shfl(aes, 4*q+1), w[4*q+1], zd);
            zd = fmaf(__shfl(aes, 4*q+2), w[4*q+2], zd);
            zd = fmaf(__shfl(aes, 4*q+3), w[4*q+3], zd);
        }
        const float inv = 1.f / fmaxf((float)deg, 1.f);
        out[(size_t)n * D + dimp] = fmaf(inv, zd, (deg > 0 ? lwbl : 0.f) + lbl);
    }
}

// ---------------- tier C (tiny ws): atomic version ----------------

__global__ void __launch_bounds__(256) edge_scatter_fb(
    const float* __restrict__ x, const int* __restrict__ ei,
    const float* __restrict__ ea, const float* __restrict__ ew,
    const float* __restrict__ eb, float* __restrict__ agg, float* __restrict__ deg) {
    const int lane = threadIdx.x & 63;
    const int wid  = blockIdx.x * (blockDim.x >> 6) + (threadIdx.x >> 6);
    const int nw   = gridDim.x * (blockDim.x >> 6);
    float w[ED];
#pragma unroll
    for (int k = 0; k < ED; ++k) w[k] = ew[lane * ED + k];
    const float b = eb[lane];
    for (int e = wid; e < N_EDGES; e += nw) {
        const int r = ei[e];
        const int c = ei[N_EDGES + e];
        const float4* ea4 = (const float4*)(ea + (size_t)e * ED);
        float acc = b;
#pragma unroll
        for (int q = 0; q < ED / 4; ++q) {
            float4 v = ea4[q];
            acc = fmaf(v.x, w[4*q+0], acc); acc = fmaf(v.y, w[4*q+1], acc);
            acc = fmaf(v.z, w[4*q+2], acc); acc = fmaf(v.w, w[4*q+3], acc);
        }
        acc += x[(size_t)r * D + lane];
        atomicAdd(&agg[(size_t)c * D + lane], acc);
        if (lane == 0) atomicAdd(&deg[c], 1.0f);
    }
}

__global__ void __launch_bounds__(256) node_linear_fb(
    float* __restrict__ agg, const float* __restrict__ deg,
    const float* __restrict__ lw, const float* __restrict__ lb) {
    const int lane = threadIdx.x & 63;
    const int wid  = blockIdx.x * (blockDim.x >> 6) + (threadIdx.x >> 6);
    const int nw   = gridDim.x * (blockDim.x >> 6);
    float w[D];
#pragma unroll
    for (int k = 0; k < D; ++k) w[k] = lw[lane * D + k];
    const float b = lb[lane];
    for (int n = wid; n < N_NODES; n += nw) {
        const float inv = 1.0f / fmaxf(deg[n], 1.0f);
        const float4* a4 = (const float4*)(agg + (size_t)n * D);
        float dot = 0.0f;
#pragma unroll
        for (int q = 0; q < D / 4; ++q) {
            float4 v = a4[q];
            dot = fmaf(v.x, w[4*q+0], dot); dot = fmaf(v.y, w[4*q+1], dot);
            dot = fmaf(v.z, w[4*q+2], dot); dot = fmaf(v.w, w[4*q+3], dot);
        }
        agg[(size_t)n * D + lane] = fmaf(inv, dot, b);
    }
}

// ---------------- launch ----------------

extern "C" void kernel_launch(void* const* d_in, const int* in_sizes, int n_in,
                              void* d_out, int out_size, void* d_ws, size_t ws_size,
                              hipStream_t stream) {
    const float* x  = (const float*)d_in[0];
    const int*   ei = (const int*)d_in[1];     // [2][E]: rows then cols
    const float* ea = (const float*)d_in[2];
    const float* lw = (const float*)d_in[3];
    const float* lb = (const float*)d_in[4];
    const float* ew = (const float*)d_in[5];
    const float* eb = (const float*)d_in[6];
    const int* row = ei;
    const int* col = ei + N_EDGES;

    char* ws = (char*)d_ws;
    float* zout = (float*)d_out;

    // ws layout (~41 MB)
    const size_t W_EREC = 0;                                   // N*32 int2 = 25,600,000
    const size_t W_XL   = (size_t)N_NODES * CAP * 8;           // N*64 bf16 = 12,800,000
    const size_t W_CNT  = W_XL + (size_t)N_NODES * D * 2;      //    400,000
    const size_t W_OVFC = W_CNT + (size_t)N_NODES * 4;         //         16
    const size_t W_OVF  = W_OVFC + 16;                         //  2,097,152
    const size_t W_CMAT = W_OVF + (size_t)OVF_CAP * 16;        //      8,192
    const size_t W_LWB  = W_CMAT + D * ED * 4;                 //        256
    const size_t REQ    = W_LWB + D * 4;

    if (ws_size >= REQ) {
        int2*   erec = (int2*)(ws + W_EREC);
        ushort* xl   = (ushort*)(ws + W_XL);
        int*    cnt  = (int*)(ws + W_CNT);
        int*    ovfc = (int*)(ws + W_OVFC);
        int4*   ovf  = (int4*)(ws + W_OVF);
        float*  Cmat = (float*)(ws + W_CMAT);
        float*  lwbv = (float*)(ws + W_LWB);

        hipMemsetAsync(cnt, 0, (size_t)N_NODES * sizeof(int) + 16, stream);
        scatter_xcd_k  <<<2048, 256, 0, stream>>>(row, col, cnt, erec, ovf, ovfc);
        xl16_combine_k <<<1025, 256, 0, stream>>>(x, lw, xl, ew, eb, Cmat, lwbv);
        agg_v6_k       <<<4096, 256, 0, stream>>>(xl, ea, cnt, erec, ovf, ovfc,
                                                  Cmat, lwbv, lb, zout);
    } else {
        float* deg = (float*)d_ws;
        hipMemsetAsync(zout, 0, (size_t)N_NODES * D * sizeof(float), stream);
        hipMemsetAsync(deg, 0, (size_t)N_NODES * sizeof(float), stream);
        edge_scatter_fb<<<2048, 256, 0, stream>>>(x, ei, ea, ew, eb, zout, deg);
        node_linear_fb <<<1024, 256, 0, stream>>>(zout, deg, lw, lb);
    }
}